// Round 1
// baseline (215.062 us; speedup 1.0000x reference)
//
#include <hip/hip_runtime.h>
#include <hip/hip_bf16.h>

#define HIDDEN 512
#define M_PER_TOKEN 32

// One block (256 threads = 4 waves) per token.
// Wave w handles m = w*8 .. w*8+7.
// Each lane owns a contiguous 8-float (32B) slice of the 512-float row:
// wave's 64 lanes x 32B = 2KB = full row, perfectly coalesced (2x dwordx4/lane).
__global__ __launch_bounds__(256) void dynamic_ffn_kernel(
    const float* __restrict__ input,    // [8192, 512]
    const int*   __restrict__ mask,     // [8192, 32]
    const float* __restrict__ weight,   // [50000, 512]
    const float* __restrict__ bias,     // [50000]
    float*       __restrict__ out,      // [8192, 32]
    int n_tokens)
{
    const int token = blockIdx.x;
    if (token >= n_tokens) return;

    const int wave = threadIdx.x >> 6;   // 0..3
    const int lane = threadIdx.x & 63;   // 0..63

    // Per-lane input slice (registers). Wave-coalesced 2KB read; the 4 waves
    // of the block re-read the same row, L1 absorbs it (negligible vs 64KB
    // of gathered weight per block).
    const float* in_row = input + (size_t)token * HIDDEN + lane * 8;
    const float4 x0 = *(const float4*)(in_row);
    const float4 x1 = *(const float4*)(in_row + 4);

    const int*  midx = mask + (size_t)token * M_PER_TOKEN + wave * 8;
    float*      orow = out  + (size_t)token * M_PER_TOKEN + wave * 8;

    // Load all 8 indices up front (wave-uniform per j after broadcast isn't
    // needed — each lane loads the same address, L1 broadcast).
    int idx[8];
#pragma unroll
    for (int j = 0; j < 8; ++j) idx[j] = midx[j];

    // Issue all weight loads + dot products; unrolled so up to 16 dwordx4
    // gathers are in flight per wave (hides random-access latency).
    float acc[8];
#pragma unroll
    for (int j = 0; j < 8; ++j) {
        const float* w = weight + (size_t)idx[j] * HIDDEN + lane * 8;
        const float4 w0 = *(const float4*)(w);
        const float4 w1 = *(const float4*)(w + 4);
        acc[j] = x0.x * w0.x + x0.y * w0.y + x0.z * w0.z + x0.w * w0.w
               + x1.x * w1.x + x1.y * w1.y + x1.z * w1.z + x1.w * w1.w;
    }

    // 64-lane reductions, one per m; lane 0 finishes with bias + relu.
#pragma unroll
    for (int j = 0; j < 8; ++j) {
        float p = acc[j];
#pragma unroll
        for (int off = 32; off > 0; off >>= 1)
            p += __shfl_down(p, off, 64);
        if (lane == 0) {
            float r = p + bias[idx[j]];
            orow[j] = r > 0.0f ? r : 0.0f;
        }
    }
}

extern "C" void kernel_launch(void* const* d_in, const int* in_sizes, int n_in,
                              void* d_out, int out_size, void* d_ws, size_t ws_size,
                              hipStream_t stream) {
    const float* input  = (const float*)d_in[0];   // [4,2048,512] fp32
    const int*   mask   = (const int*)  d_in[1];   // [4,2048,32] int32
    const float* weight = (const float*)d_in[2];   // [50000,512] fp32
    const float* bias   = (const float*)d_in[3];   // [50000] fp32
    float*       out    = (float*)d_out;           // [4,2048,32] fp32

    const int n_tokens = in_sizes[0] / HIDDEN;     // 8192

    dynamic_ffn_kernel<<<n_tokens, 256, 0, stream>>>(
        input, mask, weight, bias, out, n_tokens);
}